// Round 1
// baseline (3091.223 us; speedup 1.0000x reference)
//
#include <hip/hip_runtime.h>
#include <math.h>

#define T_LEN 2048
#define B_SZ 4
#define D_MODEL 1024
#define NH 16
#define HD 64
#define BH_TOT (B_SZ*NH)

// C = A(MxK) * W(NxK)^T + bias
// mode 0: C[m*N+n]
// mode 1: scatter to q/k/v in [b][h][t][hd] layout (m = t*B+b, n = which*1024 + h*64 + hd)
__global__ __launch_bounds__(256) void gemm_bt_kernel(
    const float* __restrict__ A, const float* __restrict__ W,
    const float* __restrict__ bias, float* __restrict__ C,
    int M, int N, int K, int mode,
    float* __restrict__ qw, float* __restrict__ kw, float* __restrict__ vw)
{
  __shared__ float As[64][17];
  __shared__ float Ws[64][17];
  const int tid = threadIdx.x;
  const int tx = tid & 15, ty = tid >> 4;
  const int n0 = blockIdx.x * 64, m0 = blockIdx.y * 64;
  const int lr = tid >> 2, lc = (tid & 3) << 2;

  float acc[4][4];
#pragma unroll
  for (int i = 0; i < 4; ++i)
#pragma unroll
    for (int j = 0; j < 4; ++j) acc[i][j] = 0.f;

  for (int k0 = 0; k0 < K; k0 += 16) {
    const float4 av = *(const float4*)(A + (size_t)(m0 + lr) * K + k0 + lc);
    const float4 wv = *(const float4*)(W + (size_t)(n0 + lr) * K + k0 + lc);
    __syncthreads();                 // previous compute done before LDS overwrite
    As[lr][lc]   = av.x; As[lr][lc+1] = av.y; As[lr][lc+2] = av.z; As[lr][lc+3] = av.w;
    Ws[lr][lc]   = wv.x; Ws[lr][lc+1] = wv.y; Ws[lr][lc+2] = wv.z; Ws[lr][lc+3] = wv.w;
    __syncthreads();                 // tiles ready
#pragma unroll
    for (int kk = 0; kk < 16; ++kk) {
      float a[4], b[4];
#pragma unroll
      for (int i = 0; i < 4; ++i) a[i] = As[ty*4 + i][kk];
#pragma unroll
      for (int j = 0; j < 4; ++j) b[j] = Ws[tx*4 + j][kk];
#pragma unroll
      for (int i = 0; i < 4; ++i)
#pragma unroll
        for (int j = 0; j < 4; ++j) acc[i][j] += a[i] * b[j];
    }
  }

  if (mode == 0) {
#pragma unroll
    for (int i = 0; i < 4; ++i) {
      const int m = m0 + ty*4 + i;
#pragma unroll
      for (int j = 0; j < 4; ++j) {
        const int n = n0 + tx*4 + j;
        C[(size_t)m * N + n] = acc[i][j] + bias[n];
      }
    }
  } else {
    // n-tile (64 wide, 64-aligned) lies within exactly one (which, h)
    const int which = n0 >> 10;
    const int h = (n0 >> 6) & (NH - 1);
    float* dst = (which == 0) ? qw : (which == 1) ? kw : vw;
    const int hd0 = tx * 4;
#pragma unroll
    for (int i = 0; i < 4; ++i) {
      const int m = m0 + ty*4 + i;
      const int t = m >> 2;          // m = t*B + b, B=4
      const int b = m & 3;
      float* p = dst + ((size_t)(b * NH + h) * T_LEN + t) * HD + hd0;
#pragma unroll
      for (int j = 0; j < 4; ++j) p[j] = acc[i][j] + bias[n0 + tx*4 + j];
    }
  }
}

// In-place RoPE on q and k, layout [bh][t][hd]; pairs (i, i+32) share cos/sin.
__global__ void rope_kernel(float* __restrict__ q, float* __restrict__ k)
{
  const int idx = blockIdx.x * blockDim.x + threadIdx.x;
  const int total = BH_TOT * T_LEN * (HD / 2);   // 2^22
  if (idx >= total) return;
  const int i  = idx & 31;
  const int t  = (idx >> 5) & (T_LEN - 1);
  const int bh = idx >> 16;                      // 2048*32 = 2^16 per bh
  const float inv_freq = powf(10000.f, -(float)i / 32.f);
  const float ang = (float)t * inv_freq;
  float s, c;
  sincosf(ang, &s, &c);                          // precise path (large args)
  const size_t base = ((size_t)bh * T_LEN + t) * HD;
  const float q1 = q[base + i], q2 = q[base + i + 32];
  q[base + i]      = q1 * c - q2 * s;
  q[base + i + 32] = q2 * c + q1 * s;
  const float k1 = k[base + i], k2 = k[base + i + 32];
  k[base + i]      = k1 * c - k2 * s;
  k[base + i + 32] = k2 * c + k1 * s;
}

// Flash-style causal attention. Block = one (b,h) x 64-query tile, 256 threads.
// Thread (qr = tid>>2, quarter = tid&3): scores for 16 keys, PV for 16 dims.
__global__ __launch_bounds__(256) void attn_kernel(
    const float* __restrict__ Qg, const float* __restrict__ Kg,
    const float* __restrict__ Vg, float* __restrict__ ctx)
{
  __shared__ float Qs[64][65];
  __shared__ float Ks[64][65];   // reused as P buffer after scores
  __shared__ float Vs[64][65];
  const int tid = threadIdx.x;
  const int bh = blockIdx.x;
  const int b = bh >> 4, h = bh & 15;
  const int qb = blockIdx.y;
  const int q0 = qb * 64;
  const int qr = tid >> 2;
  const int quarter = tid & 3;
  const int qg = q0 + qr;
  const size_t rowbase = (size_t)bh * T_LEN;

  for (int i = tid; i < 64 * 64; i += 256) {
    const int r = i >> 6, cc = i & 63;
    Qs[r][cc] = Qg[(rowbase + q0 + r) * HD + cc];
  }

  float m = -1e30f, l = 0.f;
  float c[16];
#pragma unroll
  for (int j = 0; j < 16; ++j) c[j] = 0.f;

  for (int kb = 0; kb <= qb; ++kb) {
    const int s0 = kb * 64;
    for (int i = tid; i < 64 * 64; i += 256) {
      const int r = i >> 6, cc = i & 63;
      Ks[r][cc] = Kg[(rowbase + s0 + r) * HD + cc];
      Vs[r][cc] = Vg[(rowbase + s0 + r) * HD + cc];
    }
    __syncthreads();

    float sv[16];
#pragma unroll
    for (int j = 0; j < 16; ++j) sv[j] = 0.f;
    for (int kk = 0; kk < 64; ++kk) {
      const float qv = Qs[qr][kk];
#pragma unroll
      for (int j = 0; j < 16; ++j) sv[j] += qv * Ks[quarter * 16 + j][kk];
    }
#pragma unroll
    for (int j = 0; j < 16; ++j) {
      const int sg = s0 + quarter * 16 + j;
      sv[j] = (sg <= qg) ? sv[j] * 0.125f : -1e30f;
    }

    // online softmax: row reduce across the 4 lanes sharing qr (lanes 4k..4k+3)
    float bm = sv[0];
#pragma unroll
    for (int j = 1; j < 16; ++j) bm = fmaxf(bm, sv[j]);
    bm = fmaxf(bm, __shfl_xor(bm, 1));
    bm = fmaxf(bm, __shfl_xor(bm, 2));
    const float mnew = fmaxf(m, bm);
    const float alpha = __expf(m - mnew);
    float psum = 0.f;
#pragma unroll
    for (int j = 0; j < 16; ++j) {
      sv[j] = __expf(sv[j] - mnew);
      psum += sv[j];
    }
    psum += __shfl_xor(psum, 1);
    psum += __shfl_xor(psum, 2);
    l = l * alpha + psum;
    m = mnew;
#pragma unroll
    for (int j = 0; j < 16; ++j) c[j] *= alpha;

    __syncthreads();               // everyone done reading Ks for scores
#pragma unroll
    for (int j = 0; j < 16; ++j) Ks[qr][quarter * 16 + j] = sv[j];
    __syncthreads();               // P ready

    const int d0 = quarter * 16;
#pragma unroll 8
    for (int s = 0; s < 64; ++s) {
      const float pv = Ks[qr][s];
#pragma unroll
      for (int j = 0; j < 16; ++j) c[j] += pv * Vs[s][d0 + j];
    }
    __syncthreads();               // before next K/V overwrite
  }

  const float inv = 1.f / l;
  const int d0 = quarter * 16;
  float* op = ctx + ((size_t)qg * B_SZ + b) * D_MODEL + h * HD + d0;
#pragma unroll
  for (int j = 0; j < 16; ++j) op[j] = c[j] * inv;
}

extern "C" void kernel_launch(void* const* d_in, const int* in_sizes, int n_in,
                              void* d_out, int out_size, void* d_ws, size_t ws_size,
                              hipStream_t stream) {
  const float* x    = (const float*)d_in[0];
  // d_in[1] = attention_mask: deterministic causal triu(k=1) -> implemented directly
  const float* Wqkv = (const float*)d_in[2];
  const float* bqkv = (const float*)d_in[3];
  const float* Wout = (const float*)d_in[4];
  const float* bout = (const float*)d_in[5];
  float* out = (float*)d_out;

  const size_t per = (size_t)BH_TOT * T_LEN * HD;   // 8,388,608 floats
  float* qw  = (float*)d_ws;
  float* kw  = qw + per;
  float* vw  = kw + per;
  float* ctx = vw + per;                            // total ws use: 128 MiB

  // 1) QKV GEMM + bias, scatter into [b][h][t][hd]
  dim3 g1(3 * D_MODEL / 64, (T_LEN * B_SZ) / 64);
  gemm_bt_kernel<<<g1, 256, 0, stream>>>(x, Wqkv, bqkv, nullptr,
                                         T_LEN * B_SZ, 3 * D_MODEL, D_MODEL, 1,
                                         qw, kw, vw);
  // 2) RoPE in place on q, k
  const int rope_total = BH_TOT * T_LEN * (HD / 2);
  rope_kernel<<<(rope_total + 255) / 256, 256, 0, stream>>>(qw, kw);

  // 3) causal flash attention -> ctx in (T,B,D) layout
  dim3 g2(BH_TOT, T_LEN / 64);
  attn_kernel<<<g2, 256, 0, stream>>>(qw, kw, vw, ctx);

  // 4) output projection
  dim3 g3(D_MODEL / 64, (T_LEN * B_SZ) / 64);
  gemm_bt_kernel<<<g3, 256, 0, stream>>>(ctx, Wout, bout, out,
                                         T_LEN * B_SZ, D_MODEL, D_MODEL, 0,
                                         nullptr, nullptr, nullptr);
}

// Round 2
// 1384.242 us; speedup vs baseline: 2.2332x; 2.2332x over previous
//
#include <hip/hip_runtime.h>
#include <math.h>

#define T_LEN 2048
#define B_SZ 4
#define D_MODEL 1024
#define NH 16
#define HD 64
#define BH_TOT (B_SZ*NH)

typedef __attribute__((ext_vector_type(8))) short bf16x8;
typedef __attribute__((ext_vector_type(4))) float f32x4;
typedef __attribute__((ext_vector_type(8))) unsigned short u16x8;

union U8 { unsigned int u[4]; bf16x8 v; };

static __device__ __forceinline__ unsigned short f2bf(float f) {
  unsigned int x = __float_as_uint(f);
  x += 0x7fffu + ((x >> 16) & 1u);
  return (unsigned short)(x >> 16);
}

// ---------------- fp32 GEMM (unchanged, known-good) ----------------
// C = A(MxK) * W(NxK)^T + bias
// mode 0: C[m*N+n];  mode 1: scatter q/k/v fp32 into [b][h][t][hd]
__global__ __launch_bounds__(256) void gemm_bt_kernel(
    const float* __restrict__ A, const float* __restrict__ W,
    const float* __restrict__ bias, float* __restrict__ C,
    int M, int N, int K, int mode,
    float* __restrict__ qw, float* __restrict__ kw, float* __restrict__ vw)
{
  __shared__ float As[64][17];
  __shared__ float Ws[64][17];
  const int tid = threadIdx.x;
  const int tx = tid & 15, ty = tid >> 4;
  const int n0 = blockIdx.x * 64, m0 = blockIdx.y * 64;
  const int lr = tid >> 2, lc = (tid & 3) << 2;

  float acc[4][4];
#pragma unroll
  for (int i = 0; i < 4; ++i)
#pragma unroll
    for (int j = 0; j < 4; ++j) acc[i][j] = 0.f;

  for (int k0 = 0; k0 < K; k0 += 16) {
    const float4 av = *(const float4*)(A + (size_t)(m0 + lr) * K + k0 + lc);
    const float4 wv = *(const float4*)(W + (size_t)(n0 + lr) * K + k0 + lc);
    __syncthreads();
    As[lr][lc]   = av.x; As[lr][lc+1] = av.y; As[lr][lc+2] = av.z; As[lr][lc+3] = av.w;
    Ws[lr][lc]   = wv.x; Ws[lr][lc+1] = wv.y; Ws[lr][lc+2] = wv.z; Ws[lr][lc+3] = wv.w;
    __syncthreads();
#pragma unroll
    for (int kk = 0; kk < 16; ++kk) {
      float a[4], b[4];
#pragma unroll
      for (int i = 0; i < 4; ++i) a[i] = As[ty*4 + i][kk];
#pragma unroll
      for (int j = 0; j < 4; ++j) b[j] = Ws[tx*4 + j][kk];
#pragma unroll
      for (int i = 0; i < 4; ++i)
#pragma unroll
        for (int j = 0; j < 4; ++j) acc[i][j] += a[i] * b[j];
    }
  }

  if (mode == 0) {
#pragma unroll
    for (int i = 0; i < 4; ++i) {
      const int m = m0 + ty*4 + i;
#pragma unroll
      for (int j = 0; j < 4; ++j) {
        const int n = n0 + tx*4 + j;
        C[(size_t)m * N + n] = acc[i][j] + bias[n];
      }
    }
  } else {
    const int which = n0 >> 10;
    const int h = (n0 >> 6) & (NH - 1);
    float* dst = (which == 0) ? qw : (which == 1) ? kw : vw;
    const int hd0 = tx * 4;
#pragma unroll
    for (int i = 0; i < 4; ++i) {
      const int m = m0 + ty*4 + i;
      const int t = m >> 2;
      const int b = m & 3;
      float* p = dst + ((size_t)(b * NH + h) * T_LEN + t) * HD + hd0;
#pragma unroll
      for (int j = 0; j < 4; ++j) p[j] = acc[i][j] + bias[n0 + tx*4 + j];
    }
  }
}

// ---------------- RoPE -> bf16 q (pre-scaled by 1/8) and bf16 k ----------------
__global__ void rope_bf16_kernel(const float* __restrict__ q, const float* __restrict__ k,
                                 unsigned short* __restrict__ qb, unsigned short* __restrict__ kb)
{
  const int idx = blockIdx.x * blockDim.x + threadIdx.x;
  const int i  = idx & 31;
  const int t  = (idx >> 5) & (T_LEN - 1);
  const int bh = idx >> 16;
  const float inv_freq = powf(10000.f, -(float)i / 32.f);
  float s, c;
  sincosf((float)t * inv_freq, &s, &c);
  const size_t base = ((size_t)bh * T_LEN + t) * HD;
  const float q1 = q[base + i], q2 = q[base + i + 32];
  qb[base + i]      = f2bf((q1 * c - q2 * s) * 0.125f);
  qb[base + i + 32] = f2bf((q2 * c + q1 * s) * 0.125f);
  const float k1 = k[base + i], k2 = k[base + i + 32];
  kb[base + i]      = f2bf(k1 * c - k2 * s);
  kb[base + i + 32] = f2bf(k2 * c + k1 * s);
}

// ---------------- V transpose: fp32 [bh][t][64] -> bf16 [bh][64][2048] ----------------
__global__ __launch_bounds__(256) void vtrans_kernel(const float* __restrict__ v,
                                                     unsigned short* __restrict__ vt)
{
  __shared__ float Ls[64][65];
  const int tid = threadIdx.x;
  const int bh = blockIdx.x, t0 = blockIdx.y * 64;
  {
    const int r = tid >> 2, c0 = (tid & 3) * 16;
    const float* src = v + ((size_t)bh * T_LEN + t0 + r) * HD + c0;
#pragma unroll
    for (int j = 0; j < 4; ++j) {
      float4 f = *(const float4*)(src + j * 4);
      Ls[r][c0 + j*4 + 0] = f.x; Ls[r][c0 + j*4 + 1] = f.y;
      Ls[r][c0 + j*4 + 2] = f.z; Ls[r][c0 + j*4 + 3] = f.w;
    }
  }
  __syncthreads();
  {
    const int d = tid >> 2, u0 = (tid & 3) * 16;
    u16x8 o0, o1;
#pragma unroll
    for (int e = 0; e < 8; ++e) o0[e] = f2bf(Ls[u0 + e][d]);
#pragma unroll
    for (int e = 0; e < 8; ++e) o1[e] = f2bf(Ls[u0 + 8 + e][d]);
    unsigned short* dst = vt + ((size_t)bh * HD + d) * T_LEN + t0 + u0;
    *(u16x8*)dst = o0;
    *(u16x8*)(dst + 8) = o1;
  }
}

// ---------------- bf16 MFMA flash attention ----------------
// Block: (bh, q-block of 64). 4 waves; wave w owns q rows [q0+16w, q0+16w+16).
// S^T = mfma(K, Q): lane holds S[s = st*16 + (l>>4)*4 + reg][q = l&15].
// ctx = mfma(P, V): lane holds ctx[q = (l>>4)*4 + reg][d = dt*16 + (l&15)].
__global__ __launch_bounds__(256) void attn_mfma_kernel(
    const unsigned short* __restrict__ Qb,   // [bh][t][64] bf16, pre-scaled 1/8
    const unsigned short* __restrict__ Kb,   // [bh][t][64] bf16
    const unsigned short* __restrict__ Vt,   // [bh][64][2048] bf16 (transposed)
    float* __restrict__ ctx)                 // (T, B, D) fp32
{
  __shared__ unsigned short Ks[64 * 64];     // [s][64 d], XOR-swizzled rows
  __shared__ unsigned short Vs[64 * 64];     // [d][64 s], XOR-swizzled rows
  const int tid = threadIdx.x;
  const int l = tid & 63;
  const int w = tid >> 6;
  const int lq = l & 15, lg = l >> 4;
  const int bh = blockIdx.x, qbi = blockIdx.y;
  const int b = bh >> 4, h = bh & 15;
  const size_t tb = (size_t)bh * T_LEN;

  const int q0 = qbi * 64 + w * 16;
  bf16x8 qf0, qf1;
  {
    const unsigned short* qr = Qb + (tb + q0 + lq) * HD + lg * 8;
    qf0 = *(const bf16x8*)qr;
    qf1 = *(const bf16x8*)(qr + 32);
  }

  f32x4 acc[4];
#pragma unroll
  for (int dt = 0; dt < 4; ++dt)
#pragma unroll
    for (int r2 = 0; r2 < 4; ++r2) acc[dt][r2] = 0.f;
  float mrun = -1e30f, lsum = 0.f;
  const int qg = q0 + lq;                    // this lane's softmax row (global)

  for (int kbi = 0; kbi <= qbi; ++kbi) {
    const int s0 = kbi * 64;
    __syncthreads();                         // prev compute done before overwrite
    {
      const int r = tid >> 3, c = tid & 7;
      const unsigned short* kg = Kb + (tb + s0 + r) * HD + c * 8;
      bf16x8 k0 = *(const bf16x8*)kg;
      bf16x8 k1 = *(const bf16x8*)(kg + 32 * HD);
      const unsigned short* vg = Vt + ((size_t)bh * HD + r) * T_LEN + s0 + c * 8;
      bf16x8 v0 = *(const bf16x8*)vg;
      bf16x8 v1 = *(const bf16x8*)(vg + 32 * T_LEN);
      const int xk = (c * 16) ^ ((r & 7) << 4);
      *(bf16x8*)((char*)Ks + r * 128 + xk)        = k0;
      *(bf16x8*)((char*)Ks + (r + 32) * 128 + xk) = k1;
      *(bf16x8*)((char*)Vs + r * 128 + xk)        = v0;
      *(bf16x8*)((char*)Vs + (r + 32) * 128 + xk) = v1;
    }
    __syncthreads();                         // tiles ready

    const bool diag = (kbi == qbi);
    const int stMax = diag ? (w + 1) : 4;

    f32x4 sv[4];
#pragma unroll
    for (int st = 0; st < 4; ++st)
#pragma unroll
      for (int r2 = 0; r2 < 4; ++r2) sv[st][r2] = -1e30f;

#pragma unroll
    for (int st = 0; st < 4; ++st) if (st < stMax) {
      const int r = st * 16 + lq;
      const int x = (r & 7) << 4;
      bf16x8 ka0 = *(const bf16x8*)((const char*)Ks + r * 128 + ((lg * 16) ^ x));
      bf16x8 ka1 = *(const bf16x8*)((const char*)Ks + r * 128 + (((lg + 4) * 16) ^ x));
      f32x4 z;
#pragma unroll
      for (int r2 = 0; r2 < 4; ++r2) z[r2] = 0.f;
      z = __builtin_amdgcn_mfma_f32_16x16x32_bf16(ka1, qf1, z, 0, 0, 0);
      z = __builtin_amdgcn_mfma_f32_16x16x32_bf16(ka0, qf0, z, 0, 0, 0);
      sv[st] = z;
    }

    if (diag) {
#pragma unroll
      for (int st = 0; st < 4; ++st)
#pragma unroll
        for (int r2 = 0; r2 < 4; ++r2) {
          const int sg = s0 + st * 16 + lg * 4 + r2;
          if (sg > qg) sv[st][r2] = -1e30f;
        }
    }

    // online softmax (row = q = l&15; reduce across the 4 lane-groups)
    float tmax = -1e30f;
#pragma unroll
    for (int st = 0; st < 4; ++st)
#pragma unroll
      for (int r2 = 0; r2 < 4; ++r2) tmax = fmaxf(tmax, sv[st][r2]);
    tmax = fmaxf(tmax, __shfl_xor(tmax, 16));
    tmax = fmaxf(tmax, __shfl_xor(tmax, 32));
    const float mnew = fmaxf(mrun, tmax);
    const float alpha = __expf(mrun - mnew);
    float p[4][4];
    float ps = 0.f;
#pragma unroll
    for (int st = 0; st < 4; ++st)
#pragma unroll
      for (int r2 = 0; r2 < 4; ++r2) {
        p[st][r2] = __expf(sv[st][r2] - mnew);
        ps += p[st][r2];
      }
    ps += __shfl_xor(ps, 16);
    ps += __shfl_xor(ps, 32);
    lsum = lsum * alpha + ps;
    mrun = mnew;

    // redistribute alpha into the ctx accumulator's q-mapping (q = lg*4+r)
    float a4[4];
#pragma unroll
    for (int r2 = 0; r2 < 4; ++r2) a4[r2] = __shfl(alpha, lg * 4 + r2);
#pragma unroll
    for (int dt = 0; dt < 4; ++dt)
#pragma unroll
      for (int r2 = 0; r2 < 4; ++r2) acc[dt][r2] *= a4[r2];

    // pack P to bf16 pairs (T12)
    unsigned int lo[4], hi[4];
#pragma unroll
    for (int st = 0; st < 4; ++st) {
      asm("v_cvt_pk_bf16_f32 %0, %1, %2" : "=v"(lo[st]) : "v"(p[st][0]), "v"(p[st][1]));
      asm("v_cvt_pk_bf16_f32 %0, %1, %2" : "=v"(hi[st]) : "v"(p[st][2]), "v"(p[st][3]));
    }

    // exchange into PV A-fragments and do PV MFMAs
    const int kcMax = diag ? ((w >> 1) + 1) : 2;
    const int srcA = lq + 32 * (lg & 1);
    const bool hiT = ((lg >> 1) & 1) != 0;
#pragma unroll
    for (int kc = 0; kc < 2; ++kc) if (kc < kcMax) {
      U8 pa;
      {
        unsigned int ta = __shfl(lo[2*kc], srcA),      tb2 = __shfl(lo[2*kc+1], srcA);
        pa.u[0] = hiT ? tb2 : ta;
      }
      {
        unsigned int ta = __shfl(hi[2*kc], srcA),      tb2 = __shfl(hi[2*kc+1], srcA);
        pa.u[1] = hiT ? tb2 : ta;
      }
      {
        unsigned int ta = __shfl(lo[2*kc], srcA + 16), tb2 = __shfl(lo[2*kc+1], srcA + 16);
        pa.u[2] = hiT ? tb2 : ta;
      }
      {
        unsigned int ta = __shfl(hi[2*kc], srcA + 16), tb2 = __shfl(hi[2*kc+1], srcA + 16);
        pa.u[3] = hiT ? tb2 : ta;
      }
#pragma unroll
      for (int dt = 0; dt < 4; ++dt) {
        const int d = dt * 16 + lq;
        bf16x8 vb = *(const bf16x8*)((const char*)Vs + d * 128 +
                                     (((4 * kc + lg) * 16) ^ ((d & 7) << 4)));
        acc[dt] = __builtin_amdgcn_mfma_f32_16x16x32_bf16(pa.v, vb, acc[dt], 0, 0, 0);
      }
    }
  }

  // epilogue: normalize and store ctx in (T,B,D)
  const float linv = 1.f / lsum;
  float l4[4];
#pragma unroll
  for (int r2 = 0; r2 < 4; ++r2) l4[r2] = __shfl(linv, lg * 4 + r2);
#pragma unroll
  for (int dt = 0; dt < 4; ++dt)
#pragma unroll
    for (int r2 = 0; r2 < 4; ++r2) {
      const int qrow = q0 + lg * 4 + r2;
      ctx[((size_t)qrow * B_SZ + b) * D_MODEL + h * HD + dt * 16 + lq] = acc[dt][r2] * l4[r2];
    }
}

extern "C" void kernel_launch(void* const* d_in, const int* in_sizes, int n_in,
                              void* d_out, int out_size, void* d_ws, size_t ws_size,
                              hipStream_t stream) {
  const float* x    = (const float*)d_in[0];
  const float* Wqkv = (const float*)d_in[2];
  const float* bqkv = (const float*)d_in[3];
  const float* Wout = (const float*)d_in[4];
  const float* bout = (const float*)d_in[5];
  float* out = (float*)d_out;

  const size_t per = (size_t)BH_TOT * T_LEN * HD;      // 8,388,608 elements
  float* qw = (float*)d_ws;                            // [0, 32 MiB)
  float* kw = qw + per;                                // [32, 64)
  float* vw = kw + per;                                // [64, 96)
  unsigned short* qb = (unsigned short*)(vw + per);    // [96, 112)
  unsigned short* kb = qb + per;                       // [112, 128)
  unsigned short* vt = (unsigned short*)d_ws;          // alias qw (dead after rope)
  float* ctx = kw;                                     // alias kw (dead after rope)

  // 1) QKV GEMM + bias -> q,k,v fp32 [bh][t][hd]
  dim3 g1(3 * D_MODEL / 64, (T_LEN * B_SZ) / 64);
  gemm_bt_kernel<<<g1, 256, 0, stream>>>(x, Wqkv, bqkv, nullptr,
                                         T_LEN * B_SZ, 3 * D_MODEL, D_MODEL, 1,
                                         qw, kw, vw);
  // 2) RoPE -> bf16 qb (scaled 1/8), kb
  const int rope_total = BH_TOT * T_LEN * (HD / 2);
  rope_bf16_kernel<<<(rope_total + 255) / 256, 256, 0, stream>>>(qw, kw, qb, kb);

  // 3) V transpose -> bf16 vt [bh][64][2048]  (overwrites qw region)
  dim3 gvt(BH_TOT, T_LEN / 64);
  vtrans_kernel<<<gvt, 256, 0, stream>>>(vw, vt);

  // 4) MFMA flash attention -> ctx (T,B,D) fp32 (overwrites kw region)
  dim3 g2(BH_TOT, T_LEN / 64);
  attn_mfma_kernel<<<g2, 256, 0, stream>>>(qb, kb, vt, ctx);

  // 5) output projection (fp32)
  dim3 g3(D_MODEL / 64, (T_LEN * B_SZ) / 64);
  gemm_bt_kernel<<<g3, 256, 0, stream>>>(ctx, Wout, bout, out,
                                         T_LEN * B_SZ, D_MODEL, D_MODEL, 0,
                                         nullptr, nullptr, nullptr);
}

// Round 3
// 223.315 us; speedup vs baseline: 13.8425x; 6.1986x over previous
//
#include <hip/hip_runtime.h>
#include <math.h>

#define T_LEN 2048
#define B_SZ 4
#define D_MODEL 1024
#define NH 16
#define HD 64
#define BH_TOT (B_SZ*NH)

typedef __attribute__((ext_vector_type(8))) short bf16x8;
typedef __attribute__((ext_vector_type(4))) float f32x4;
typedef __attribute__((ext_vector_type(8))) unsigned short u16x8;

union U8 { unsigned int u[4]; bf16x8 v; };

static __device__ __forceinline__ unsigned short f2bf(float f) {
  unsigned int x = __float_as_uint(f);
  x += 0x7fffu + ((x >> 16) & 1u);
  return (unsigned short)(x >> 16);
}
static __device__ __forceinline__ float bf2f(unsigned short u) {
  return __uint_as_float(((unsigned int)u) << 16);
}

// ---------------- fp32 -> bf16 convert (8 elems/thread) ----------------
__global__ __launch_bounds__(256) void cvt_bf16_kernel(const float* __restrict__ src,
                                                       unsigned short* __restrict__ dst,
                                                       int n8) {
  const int i = blockIdx.x * 256 + threadIdx.x;
  if (i >= n8) return;
  const float4 a = ((const float4*)src)[i * 2];
  const float4 b = ((const float4*)src)[i * 2 + 1];
  u16x8 o;
  o[0] = f2bf(a.x); o[1] = f2bf(a.y); o[2] = f2bf(a.z); o[3] = f2bf(a.w);
  o[4] = f2bf(b.x); o[5] = f2bf(b.y); o[6] = f2bf(b.z); o[7] = f2bf(b.w);
  ((u16x8*)dst)[i] = o;
}

// ---------------- bf16 MFMA GEMM: C = A(MxK) * W(NxK)^T + bias ----------------
// 128x128 tile, BK=64, 4 waves (2x2), wave tile 64x64 (4x4 frags of 16x16).
// mode 0: fp32 C[m*N+n]
// mode 1: bf16 scatter q/k/v into [bh][t][hd]  (N=3072, m = t*B+b)
__global__ __launch_bounds__(256, 2) void gemm_mfma_kernel(
    const unsigned short* __restrict__ A, const unsigned short* __restrict__ W,
    const float* __restrict__ bias, float* __restrict__ C,
    int M, int N, int K, int mode,
    unsigned short* __restrict__ qd, unsigned short* __restrict__ kd,
    unsigned short* __restrict__ vd)
{
  __shared__ unsigned short As[128 * 64];   // [row][64 bf16], XOR-swizzled rows
  __shared__ unsigned short Bs[128 * 64];
  const int tid = threadIdx.x;
  const int l = tid & 63, w = tid >> 6;
  const int lq = l & 15, lg = l >> 4;
  const int wm = w >> 1, wn = w & 1;
  const int n0 = blockIdx.x * 128, m0 = blockIdx.y * 128;

  // staging: thread -> (row group, 16B block), swizzle on LDS dest only
  const int sr = tid >> 3;                  // 0..31
  const int sb = tid & 7;                   // 0..7
  const int scol_src = sb << 4;             // linear byte col in global row
  const int scol_dst = scol_src ^ ((sr & 7) << 4);

  f32x4 acc[4][4];
#pragma unroll
  for (int mt = 0; mt < 4; ++mt)
#pragma unroll
    for (int nt = 0; nt < 4; ++nt)
#pragma unroll
      for (int r2 = 0; r2 < 4; ++r2) acc[mt][nt][r2] = 0.f;

  for (int k0 = 0; k0 < K; k0 += 64) {
    bf16x8 ar[4], br[4];
#pragma unroll
    for (int c = 0; c < 4; ++c) {
      const int row = c * 32 + sr;
      ar[c] = *(const bf16x8*)((const char*)A + ((size_t)(m0 + row) * K + k0) * 2 + scol_src);
      br[c] = *(const bf16x8*)((const char*)W + ((size_t)(n0 + row) * K + k0) * 2 + scol_src);
    }
    __syncthreads();                        // prev compute done before overwrite
#pragma unroll
    for (int c = 0; c < 4; ++c) {
      const int row = c * 32 + sr;
      *(bf16x8*)((char*)As + row * 128 + scol_dst) = ar[c];
      *(bf16x8*)((char*)Bs + row * 128 + scol_dst) = br[c];
    }
    __syncthreads();                        // tiles ready

#pragma unroll
    for (int kc = 0; kc < 2; ++kc) {
      bf16x8 af[4], bfr[4];
#pragma unroll
      for (int mt = 0; mt < 4; ++mt) {
        const int r = wm * 64 + mt * 16 + lq;
        af[mt] = *(const bf16x8*)((const char*)As + r * 128 +
                                  ((kc * 64 + lg * 16) ^ ((r & 7) << 4)));
      }
#pragma unroll
      for (int nt = 0; nt < 4; ++nt) {
        const int r = wn * 64 + nt * 16 + lq;
        bfr[nt] = *(const bf16x8*)((const char*)Bs + r * 128 +
                                   ((kc * 64 + lg * 16) ^ ((r & 7) << 4)));
      }
#pragma unroll
      for (int mt = 0; mt < 4; ++mt)
#pragma unroll
        for (int nt = 0; nt < 4; ++nt)
          acc[mt][nt] = __builtin_amdgcn_mfma_f32_16x16x32_bf16(af[mt], bfr[nt], acc[mt][nt], 0, 0, 0);
    }
  }

  // epilogue: D row = m (A-operand), col = n (B-operand); lane: col=lq, row=lg*4+r2
  if (mode == 0) {
#pragma unroll
    for (int nt = 0; nt < 4; ++nt) {
      const int n = n0 + wn * 64 + nt * 16 + lq;
      const float bv = bias[n];
#pragma unroll
      for (int mt = 0; mt < 4; ++mt)
#pragma unroll
        for (int r2 = 0; r2 < 4; ++r2) {
          const int m = m0 + wm * 64 + mt * 16 + lg * 4 + r2;
          C[(size_t)m * N + n] = acc[mt][nt][r2] + bv;
        }
    }
  } else {
#pragma unroll
    for (int nt = 0; nt < 4; ++nt) {
      const int n = n0 + wn * 64 + nt * 16 + lq;
      const float bv = bias[n];
      const int which = n >> 10;
      const int h = (n >> 6) & (NH - 1);
      const int hd = n & 63;
      unsigned short* dst = (which == 0) ? qd : (which == 1) ? kd : vd;
#pragma unroll
      for (int mt = 0; mt < 4; ++mt)
#pragma unroll
        for (int r2 = 0; r2 < 4; ++r2) {
          const int m = m0 + wm * 64 + mt * 16 + lg * 4 + r2;
          const int t = m >> 2, b = m & 3;
          dst[((size_t)(b * NH + h) * T_LEN + t) * HD + hd] = f2bf(acc[mt][nt][r2] + bv);
        }
    }
  }
}

// ---------------- RoPE in place on bf16 q (pre-scale 1/8) and k ----------------
__global__ void rope_bf16_kernel(unsigned short* __restrict__ qb, unsigned short* __restrict__ kb)
{
  const int idx = blockIdx.x * blockDim.x + threadIdx.x;
  const int i  = idx & 31;
  const int t  = (idx >> 5) & (T_LEN - 1);
  const int bh = idx >> 16;
  const float inv_freq = powf(10000.f, -(float)i / 32.f);
  float s, c;
  sincosf((float)t * inv_freq, &s, &c);
  const size_t base = ((size_t)bh * T_LEN + t) * HD;
  const float q1 = bf2f(qb[base + i]), q2 = bf2f(qb[base + i + 32]);
  qb[base + i]      = f2bf((q1 * c - q2 * s) * 0.125f);
  qb[base + i + 32] = f2bf((q2 * c + q1 * s) * 0.125f);
  const float k1 = bf2f(kb[base + i]), k2 = bf2f(kb[base + i + 32]);
  kb[base + i]      = f2bf(k1 * c - k2 * s);
  kb[base + i + 32] = f2bf(k2 * c + k1 * s);
}

// ---------------- V transpose: bf16 [bh][t][64] -> bf16 [bh][64][2048] ----------------
__global__ __launch_bounds__(256) void vtrans_kernel(const unsigned short* __restrict__ v,
                                                     unsigned short* __restrict__ vt)
{
  __shared__ unsigned short Ls[64][65];
  const int tid = threadIdx.x;
  const int bh = blockIdx.x, t0 = blockIdx.y * 64;
  {
    const int r = tid >> 2, c0 = (tid & 3) * 16;
    const unsigned short* src = v + ((size_t)bh * T_LEN + t0 + r) * HD + c0;
    u16x8 f0 = *(const u16x8*)src;
    u16x8 f1 = *(const u16x8*)(src + 8);
#pragma unroll
    for (int e = 0; e < 8; ++e) { Ls[r][c0 + e] = f0[e]; Ls[r][c0 + 8 + e] = f1[e]; }
  }
  __syncthreads();
  {
    const int d = tid >> 2, u0 = (tid & 3) * 16;
    u16x8 o0, o1;
#pragma unroll
    for (int e = 0; e < 8; ++e) { o0[e] = Ls[u0 + e][d]; o1[e] = Ls[u0 + 8 + e][d]; }
    unsigned short* dst = vt + ((size_t)bh * HD + d) * T_LEN + t0 + u0;
    *(u16x8*)dst = o0;
    *(u16x8*)(dst + 8) = o1;
  }
}

// ---------------- bf16 MFMA flash attention (unchanged math, bf16 ctx out) ----------------
__global__ __launch_bounds__(256) void attn_mfma_kernel(
    const unsigned short* __restrict__ Qb,   // [bh][t][64] bf16, pre-scaled 1/8
    const unsigned short* __restrict__ Kb,   // [bh][t][64] bf16
    const unsigned short* __restrict__ Vt,   // [bh][64][2048] bf16 (transposed)
    unsigned short* __restrict__ ctx)        // (T, B, D) bf16
{
  __shared__ unsigned short Ks[64 * 64];
  __shared__ unsigned short Vs[64 * 64];
  const int tid = threadIdx.x;
  const int l = tid & 63;
  const int w = tid >> 6;
  const int lq = l & 15, lg = l >> 4;
  const int bh = blockIdx.x, qbi = blockIdx.y;
  const int b = bh >> 4, h = bh & 15;
  const size_t tb = (size_t)bh * T_LEN;

  const int q0 = qbi * 64 + w * 16;
  bf16x8 qf0, qf1;
  {
    const unsigned short* qr = Qb + (tb + q0 + lq) * HD + lg * 8;
    qf0 = *(const bf16x8*)qr;
    qf1 = *(const bf16x8*)(qr + 32);
  }

  f32x4 acc[4];
#pragma unroll
  for (int dt = 0; dt < 4; ++dt)
#pragma unroll
    for (int r2 = 0; r2 < 4; ++r2) acc[dt][r2] = 0.f;
  float mrun = -1e30f, lsum = 0.f;
  const int qg = q0 + lq;

  for (int kbi = 0; kbi <= qbi; ++kbi) {
    const int s0 = kbi * 64;
    __syncthreads();
    {
      const int r = tid >> 3, c = tid & 7;
      const unsigned short* kg = Kb + (tb + s0 + r) * HD + c * 8;
      bf16x8 k0 = *(const bf16x8*)kg;
      bf16x8 k1 = *(const bf16x8*)(kg + 32 * HD);
      const unsigned short* vg = Vt + ((size_t)bh * HD + r) * T_LEN + s0 + c * 8;
      bf16x8 v0 = *(const bf16x8*)vg;
      bf16x8 v1 = *(const bf16x8*)(vg + 32 * T_LEN);
      const int xk = (c * 16) ^ ((r & 7) << 4);
      *(bf16x8*)((char*)Ks + r * 128 + xk)        = k0;
      *(bf16x8*)((char*)Ks + (r + 32) * 128 + xk) = k1;
      *(bf16x8*)((char*)Vs + r * 128 + xk)        = v0;
      *(bf16x8*)((char*)Vs + (r + 32) * 128 + xk) = v1;
    }
    __syncthreads();

    const bool diag = (kbi == qbi);
    const int stMax = diag ? (w + 1) : 4;

    f32x4 sv[4];
#pragma unroll
    for (int st = 0; st < 4; ++st)
#pragma unroll
      for (int r2 = 0; r2 < 4; ++r2) sv[st][r2] = -1e30f;

#pragma unroll
    for (int st = 0; st < 4; ++st) if (st < stMax) {
      const int r = st * 16 + lq;
      const int x = (r & 7) << 4;
      bf16x8 ka0 = *(const bf16x8*)((const char*)Ks + r * 128 + ((lg * 16) ^ x));
      bf16x8 ka1 = *(const bf16x8*)((const char*)Ks + r * 128 + (((lg + 4) * 16) ^ x));
      f32x4 z;
#pragma unroll
      for (int r2 = 0; r2 < 4; ++r2) z[r2] = 0.f;
      z = __builtin_amdgcn_mfma_f32_16x16x32_bf16(ka1, qf1, z, 0, 0, 0);
      z = __builtin_amdgcn_mfma_f32_16x16x32_bf16(ka0, qf0, z, 0, 0, 0);
      sv[st] = z;
    }

    if (diag) {
#pragma unroll
      for (int st = 0; st < 4; ++st)
#pragma unroll
        for (int r2 = 0; r2 < 4; ++r2) {
          const int sg = s0 + st * 16 + lg * 4 + r2;
          if (sg > qg) sv[st][r2] = -1e30f;
        }
    }

    float tmax = -1e30f;
#pragma unroll
    for (int st = 0; st < 4; ++st)
#pragma unroll
      for (int r2 = 0; r2 < 4; ++r2) tmax = fmaxf(tmax, sv[st][r2]);
    tmax = fmaxf(tmax, __shfl_xor(tmax, 16));
    tmax = fmaxf(tmax, __shfl_xor(tmax, 32));
    const float mnew = fmaxf(mrun, tmax);
    const float alpha = __expf(mrun - mnew);
    float p[4][4];
    float ps = 0.f;
#pragma unroll
    for (int st = 0; st < 4; ++st)
#pragma unroll
      for (int r2 = 0; r2 < 4; ++r2) {
        p[st][r2] = __expf(sv[st][r2] - mnew);
        ps += p[st][r2];
      }
    ps += __shfl_xor(ps, 16);
    ps += __shfl_xor(ps, 32);
    lsum = lsum * alpha + ps;
    mrun = mnew;

    float a4[4];
#pragma unroll
    for (int r2 = 0; r2 < 4; ++r2) a4[r2] = __shfl(alpha, lg * 4 + r2);
#pragma unroll
    for (int dt = 0; dt < 4; ++dt)
#pragma unroll
      for (int r2 = 0; r2 < 4; ++r2) acc[dt][r2] *= a4[r2];

    unsigned int lo[4], hi[4];
#pragma unroll
    for (int st = 0; st < 4; ++st) {
      asm("v_cvt_pk_bf16_f32 %0, %1, %2" : "=v"(lo[st]) : "v"(p[st][0]), "v"(p[st][1]));
      asm("v_cvt_pk_bf16_f32 %0, %1, %2" : "=v"(hi[st]) : "v"(p[st][2]), "v"(p[st][3]));
    }

    const int kcMax = diag ? ((w >> 1) + 1) : 2;
    const int srcA = lq + 32 * (lg & 1);
    const bool hiT = ((lg >> 1) & 1) != 0;
#pragma unroll
    for (int kc = 0; kc < 2; ++kc) if (kc < kcMax) {
      U8 pa;
      {
        unsigned int ta = __shfl(lo[2*kc], srcA),      tb2 = __shfl(lo[2*kc+1], srcA);
        pa.u[0] = hiT ? tb2 : ta;
      }
      {
        unsigned int ta = __shfl(hi[2*kc], srcA),      tb2 = __shfl(hi[2*kc+1], srcA);
        pa.u[1] = hiT ? tb2 : ta;
      }
      {
        unsigned int ta = __shfl(lo[2*kc], srcA + 16), tb2 = __shfl(lo[2*kc+1], srcA + 16);
        pa.u[2] = hiT ? tb2 : ta;
      }
      {
        unsigned int ta = __shfl(hi[2*kc], srcA + 16), tb2 = __shfl(hi[2*kc+1], srcA + 16);
        pa.u[3] = hiT ? tb2 : ta;
      }
#pragma unroll
      for (int dt = 0; dt < 4; ++dt) {
        const int d = dt * 16 + lq;
        bf16x8 vb = *(const bf16x8*)((const char*)Vs + d * 128 +
                                     (((4 * kc + lg) * 16) ^ ((d & 7) << 4)));
        acc[dt] = __builtin_amdgcn_mfma_f32_16x16x32_bf16(pa.v, vb, acc[dt], 0, 0, 0);
      }
    }
  }

  const float linv = 1.f / lsum;
  float l4[4];
#pragma unroll
  for (int r2 = 0; r2 < 4; ++r2) l4[r2] = __shfl(linv, lg * 4 + r2);
#pragma unroll
  for (int dt = 0; dt < 4; ++dt)
#pragma unroll
    for (int r2 = 0; r2 < 4; ++r2) {
      const int qrow = q0 + lg * 4 + r2;
      ctx[((size_t)qrow * B_SZ + b) * D_MODEL + h * HD + dt * 16 + lq] = f2bf(acc[dt][r2] * l4[r2]);
    }
}

extern "C" void kernel_launch(void* const* d_in, const int* in_sizes, int n_in,
                              void* d_out, int out_size, void* d_ws, size_t ws_size,
                              hipStream_t stream) {
  const float* x    = (const float*)d_in[0];
  const float* Wqkv = (const float*)d_in[2];
  const float* bqkv = (const float*)d_in[3];
  const float* Wout = (const float*)d_in[4];
  const float* bout = (const float*)d_in[5];
  float* out = (float*)d_out;

  char* wsb = (char*)d_ws;
  unsigned short* xb    = (unsigned short*)(wsb);                    // 16 MiB
  unsigned short* wqkvb = (unsigned short*)(wsb + (22ull << 20)) - 3145728; // [16,22) MiB
  unsigned short* woutb = (unsigned short*)(wsb + (22ull << 20));    // 2 MiB
  unsigned short* qb    = (unsigned short*)(wsb + (24ull << 20));    // 16 MiB
  unsigned short* kb    = (unsigned short*)(wsb + (40ull << 20));    // 16 MiB
  unsigned short* vb    = (unsigned short*)(wsb + (56ull << 20));    // 16 MiB
  unsigned short* vt    = (unsigned short*)(wsb + (72ull << 20));    // 16 MiB
  unsigned short* ctxb  = (unsigned short*)(wsb + (88ull << 20));    // 16 MiB -> 104 total

  // 0) casts to bf16
  cvt_bf16_kernel<<<(T_LEN*B_SZ*D_MODEL/8 + 255)/256, 256, 0, stream>>>(x, xb, T_LEN*B_SZ*D_MODEL/8);
  cvt_bf16_kernel<<<(3*D_MODEL*D_MODEL/8 + 255)/256, 256, 0, stream>>>(Wqkv, wqkvb, 3*D_MODEL*D_MODEL/8);
  cvt_bf16_kernel<<<(D_MODEL*D_MODEL/8 + 255)/256, 256, 0, stream>>>(Wout, woutb, D_MODEL*D_MODEL/8);

  // 1) QKV GEMM (bf16 MFMA) -> bf16 q,k,v in [bh][t][hd]
  dim3 g1(3 * D_MODEL / 128, (T_LEN * B_SZ) / 128);
  gemm_mfma_kernel<<<g1, 256, 0, stream>>>(xb, wqkvb, bqkv, nullptr,
                                           T_LEN * B_SZ, 3 * D_MODEL, D_MODEL, 1,
                                           qb, kb, vb);
  // 2) RoPE in place (q scaled by 1/8)
  const int rope_total = BH_TOT * T_LEN * (HD / 2);
  rope_bf16_kernel<<<(rope_total + 255) / 256, 256, 0, stream>>>(qb, kb);

  // 3) V transpose -> [bh][64][2048]
  dim3 gvt(BH_TOT, T_LEN / 64);
  vtrans_kernel<<<gvt, 256, 0, stream>>>(vb, vt);

  // 4) MFMA flash attention -> bf16 ctx (T,B,D)
  dim3 g2(BH_TOT, T_LEN / 64);
  attn_mfma_kernel<<<g2, 256, 0, stream>>>(qb, kb, vt, ctxb);

  // 5) output projection (bf16 MFMA, fp32 out)
  dim3 g3(D_MODEL / 128, (T_LEN * B_SZ) / 128);
  gemm_mfma_kernel<<<g3, 256, 0, stream>>>(ctxb, woutb, bout, out,
                                           T_LEN * B_SZ, D_MODEL, D_MODEL, 0,
                                           nullptr, nullptr, nullptr);
}